// Round 1
// baseline (1094.980 us; speedup 1.0000x reference)
//
#include <hip/hip_runtime.h>

typedef short short8 __attribute__((ext_vector_type(8)));
typedef float f32x4 __attribute__((ext_vector_type(4)));

#define AS1(p) ((const __attribute__((address_space(1))) void*)(p))
#define AS3(p) ((__attribute__((address_space(3))) void*)(p))

__device__ __forceinline__ unsigned short f2bf(float f) {
    unsigned int u = __float_as_uint(f);
    u += 0x7fffu + ((u >> 16) & 1u);   // RNE
    return (unsigned short)(u >> 16);
}

// ---------------- prep: x->bf16, conv_w -> [o][k] bf16, fused BN consts ----------------
__global__ __launch_bounds__(256) void prep_kernel(
    const float* __restrict__ x, const float* __restrict__ conv_w,
    const float* __restrict__ conv_b,
    const float* __restrict__ g1, const float* __restrict__ b1,
    const float* __restrict__ m1, const float* __restrict__ v1,
    const float* __restrict__ local_b,
    const float* __restrict__ g2, const float* __restrict__ b2,
    const float* __restrict__ m2, const float* __restrict__ v2,
    unsigned short* __restrict__ xbf, unsigned short* __restrict__ wct,
    float* __restrict__ scale1, float* __restrict__ bias1,
    float* __restrict__ scale2, float* __restrict__ bias2)
{
    int i = blockIdx.x * 256 + threadIdx.x;
    if (i < 2097152) {                       // 8388608 x elems as float4
        float4 v = ((const float4*)x)[i];
        ushort4 o;
        o.x = f2bf(v.x); o.y = f2bf(v.y); o.z = f2bf(v.z); o.w = f2bf(v.w);
        ((ushort4*)xbf)[i] = o;
    }
    if (i < 81920) {                         // conv_w [k=f*64+c][u] -> wct[u][k]
        int u = i & 255, k = i >> 8;
        wct[u * 320 + k] = f2bf(conv_w[i]);
    }
    if (i < 129024) {                        // bias2[l2*256+o] = s2*(local_b - m2) + b2
        int o = i & 255;
        float s = g2[o] * rsqrtf(v2[o] + 1e-3f);
        bias2[i] = s * (local_b[i] - m2[o]) + b2[o];
    }
    if (i < 256) {
        float s1 = g1[i] * rsqrtf(v1[i] + 1e-3f);
        scale1[i] = s1;
        bias1[i] = s1 * (conv_b[i] - m1[i]) + b1[i];
        scale2[i] = g2[i] * rsqrtf(v2[i] + 1e-3f);
    }
}

// ---------------- conv GEMM: M=130048 (b*508+l1), K=320, N=256; y = relu(BN1(.)) bf16 ----
__global__ __launch_bounds__(256) void conv_gemm(
    const unsigned short* __restrict__ xbf, const unsigned short* __restrict__ wct,
    const float* __restrict__ scale1, const float* __restrict__ bias1,
    unsigned short* __restrict__ y)
{
    __shared__ unsigned short As[128 * 32];   // [m][k] stride 32 elems (64 B)
    __shared__ unsigned short Bs[128 * 32];   // [o][k] stride 32 elems
    const int tid = threadIdx.x;
    const int lane = tid & 63, wave = tid >> 6;
    const int quad = lane >> 4, c16 = lane & 15;
    const int wm = (wave >> 1) * 64, wn = (wave & 1) * 64;
    const int tn = blockIdx.x * 128;
    const int m0 = blockIdx.y * 128;
    const int sr = lane >> 2, sc = lane & 3;

    f32x4 acc[4][4];
#pragma unroll
    for (int i = 0; i < 4; ++i)
#pragma unroll
        for (int j = 0; j < 4; ++j) acc[i][j] = (f32x4){0.f, 0.f, 0.f, 0.f};

    for (int k0 = 0; k0 < 320; k0 += 32) {
        __syncthreads();
#pragma unroll
        for (int j = 0; j < 2; ++j) {
            int r = wave * 32 + j * 16 + sr;
            unsigned int m = (unsigned int)(m0 + r);
            // x offset of A[m][k0]: (m + 4*(m/508))*64
            const unsigned short* srca = xbf + (size_t)(m + 4u * (m / 508u)) * 64 + k0 + sc * 8;
            __builtin_amdgcn_global_load_lds(AS1(srca), AS3(As + (wave * 32 + j * 16) * 32), 16, 0, 0);
            const unsigned short* srcb = wct + (size_t)(tn + r) * 320 + k0 + sc * 8;
            __builtin_amdgcn_global_load_lds(AS1(srcb), AS3(Bs + (wave * 32 + j * 16) * 32), 16, 0, 0);
        }
        __syncthreads();
        short8 af[4], bfv[4];
#pragma unroll
        for (int i = 0; i < 4; ++i) af[i] = *(const short8*)&As[(wm + i * 16 + c16) * 32 + quad * 8];
#pragma unroll
        for (int j = 0; j < 4; ++j) bfv[j] = *(const short8*)&Bs[(wn + j * 16 + c16) * 32 + quad * 8];
#pragma unroll
        for (int i = 0; i < 4; ++i)
#pragma unroll
            for (int j = 0; j < 4; ++j)
                acc[i][j] = __builtin_amdgcn_mfma_f32_16x16x32_bf16(af[i], bfv[j], acc[i][j], 0, 0, 0);
    }

#pragma unroll
    for (int j = 0; j < 4; ++j) {
        int o = tn + wn + j * 16 + c16;
        float s = scale1[o], bb = bias1[o];
#pragma unroll
        for (int i = 0; i < 4; ++i) {
            int m = m0 + wm + i * 16 + quad * 4;
            size_t base = (size_t)m * 256 + o;
#pragma unroll
            for (int r = 0; r < 4; ++r) {
                float v = fmaxf(s * acc[i][j][r] + bb, 0.f);
                y[base + (size_t)r * 256] = f2bf(v);
            }
        }
    }
}

// ---------------- local GEMM per l2: M=256(batch), K=1280, N=256; out = relu(BN2(.)) f32 --
__global__ __launch_bounds__(256) void local_gemm(
    const unsigned short* __restrict__ ybf, const float* __restrict__ lw,
    const float* __restrict__ scale2, const float* __restrict__ bias2,
    float* __restrict__ out)
{
    __shared__ unsigned short As[128 * 32];   // [b][k] stride 32 elems (64 B)
    __shared__ unsigned short Bs[128 * 40];   // [o][k] stride 40 elems (80 B, padded)
    const int tid = threadIdx.x;
    const int lane = tid & 63, wave = tid >> 6;
    const int quad = lane >> 4, c16 = lane & 15;
    const int wm = (wave >> 1) * 64, wn = (wave & 1) * 64;
    const int tn = blockIdx.x * 128;
    const int tm = blockIdx.y * 128;
    const int l2 = blockIdx.z;
    const int sr = lane >> 2, sc = lane & 3;
    const int so = tid & 127, hk = tid >> 7;

    const float* Wl = lw + (size_t)l2 * (1280 * 256) + tn;           // W[k][o] slice
    const unsigned short* Ab = ybf + ((size_t)tm * 508 + l2) * 256;  // + r*508*256 + k

    f32x4 acc[4][4];
#pragma unroll
    for (int i = 0; i < 4; ++i)
#pragma unroll
        for (int j = 0; j < 4; ++j) acc[i][j] = (f32x4){0.f, 0.f, 0.f, 0.f};

    for (int k0 = 0; k0 < 1280; k0 += 32) {
        __syncthreads();
        // A: async DMA, 2 calls/wave (16 rows x 64 B each)
#pragma unroll
        for (int j = 0; j < 2; ++j) {
            int r = wave * 32 + j * 16 + sr;
            const unsigned short* src = Ab + (size_t)r * (508 * 256) + k0 + sc * 8;
            __builtin_amdgcn_global_load_lds(AS1(src), AS3(As + (wave * 32 + j * 16) * 32), 16, 0, 0);
        }
        // B: fp32 W -> bf16, transposed into Bs[o][k]
#pragma unroll
        for (int p = 0; p < 4; ++p) {
            int k4 = hk * 4 + p;                    // 0..7 (group of 4 consecutive k)
            const float* ws = Wl + (size_t)(k0 + k4 * 4) * 256 + so;
            float w0 = ws[0];
            float w1 = ws[256];
            float w2 = ws[512];
            float w3 = ws[768];
            uint2 pk;
            pk.x = (unsigned int)f2bf(w0) | ((unsigned int)f2bf(w1) << 16);
            pk.y = (unsigned int)f2bf(w2) | ((unsigned int)f2bf(w3) << 16);
            *(uint2*)&Bs[so * 40 + k4 * 4] = pk;    // ds_write_b64
        }
        __syncthreads();
        short8 af[4], bfv[4];
#pragma unroll
        for (int i = 0; i < 4; ++i) af[i] = *(const short8*)&As[(wm + i * 16 + c16) * 32 + quad * 8];
#pragma unroll
        for (int j = 0; j < 4; ++j) bfv[j] = *(const short8*)&Bs[(wn + j * 16 + c16) * 40 + quad * 8];
#pragma unroll
        for (int i = 0; i < 4; ++i)
#pragma unroll
            for (int j = 0; j < 4; ++j)
                acc[i][j] = __builtin_amdgcn_mfma_f32_16x16x32_bf16(af[i], bfv[j], acc[i][j], 0, 0, 0);
    }

    const float* bp = bias2 + l2 * 256;
#pragma unroll
    for (int j = 0; j < 4; ++j) {
        int o = tn + wn + j * 16 + c16;
        float s = scale2[o], bb = bp[o];
#pragma unroll
        for (int i = 0; i < 4; ++i) {
            int b = tm + wm + i * 16 + quad * 4;
            size_t base = ((size_t)b * 504 + l2) * 256 + o;
#pragma unroll
            for (int r = 0; r < 4; ++r) {
                float v = fmaxf(s * acc[i][j][r] + bb, 0.f);
                out[base + (size_t)r * (504 * 256)] = v;
            }
        }
    }
}

extern "C" void kernel_launch(void* const* d_in, const int* in_sizes, int n_in,
                              void* d_out, int out_size, void* d_ws, size_t ws_size,
                              hipStream_t stream) {
    const float* x      = (const float*)d_in[0];
    const float* conv_w = (const float*)d_in[1];
    const float* conv_b = (const float*)d_in[2];
    const float* g1     = (const float*)d_in[3];
    const float* b1     = (const float*)d_in[4];
    const float* m1     = (const float*)d_in[5];
    const float* v1     = (const float*)d_in[6];
    const float* lw     = (const float*)d_in[7];
    const float* lb     = (const float*)d_in[8];
    const float* g2     = (const float*)d_in[9];
    const float* b2     = (const float*)d_in[10];
    const float* m2     = (const float*)d_in[11];
    const float* v2     = (const float*)d_in[12];
    float* out = (float*)d_out;

    char* w = (char*)d_ws;
    unsigned short* xbf   = (unsigned short*)(w);             // 16,777,216 B
    unsigned short* wct   = (unsigned short*)(w + 16777216);  //    163,840 B
    float*          scale1 = (float*)(w + 16941056);          //      1,024 B
    float*          bias1  = (float*)(w + 16942080);          //      1,024 B
    float*          scale2 = (float*)(w + 16943104);          //      1,024 B
    float*          bias2  = (float*)(w + 16944128);          //    516,096 B
    unsigned short* ybf   = (unsigned short*)(w + 17460224);  // 66,584,576 B  (total ~84 MB)

    hipLaunchKernelGGL(prep_kernel, dim3(8192), dim3(256), 0, stream,
                       x, conv_w, conv_b, g1, b1, m1, v1, lb, g2, b2, m2, v2,
                       xbf, wct, scale1, bias1, scale2, bias2);
    hipLaunchKernelGGL(conv_gemm, dim3(2, 1016), dim3(256), 0, stream,
                       xbf, wct, scale1, bias1, ybf);
    hipLaunchKernelGGL(local_gemm, dim3(2, 2, 504), dim3(256), 0, stream,
                       ybf, lw, scale2, bias2, out);
}

// Round 2
// 1015.433 us; speedup vs baseline: 1.0783x; 1.0783x over previous
//
#include <hip/hip_runtime.h>

typedef short short8 __attribute__((ext_vector_type(8)));
typedef float f32x4 __attribute__((ext_vector_type(4)));

#define AS1(p) ((const __attribute__((address_space(1))) void*)(p))
#define AS3(p) ((__attribute__((address_space(3))) void*)(p))

__device__ __forceinline__ unsigned short f2bf(float f) {
    unsigned int u = __float_as_uint(f);
    u += 0x7fffu + ((u >> 16) & 1u);   // RNE
    return (unsigned short)(u >> 16);
}

// ---------------- prep: x->bf16, conv_w -> [o][k] bf16, fused BN consts ----------------
__global__ __launch_bounds__(256) void prep_kernel(
    const float* __restrict__ x, const float* __restrict__ conv_w,
    const float* __restrict__ conv_b,
    const float* __restrict__ g1, const float* __restrict__ b1,
    const float* __restrict__ m1, const float* __restrict__ v1,
    const float* __restrict__ local_b,
    const float* __restrict__ g2, const float* __restrict__ b2,
    const float* __restrict__ m2, const float* __restrict__ v2,
    unsigned short* __restrict__ xbf, unsigned short* __restrict__ wct,
    float* __restrict__ scale1, float* __restrict__ bias1,
    float* __restrict__ scale2, float* __restrict__ bias2)
{
    int i = blockIdx.x * 256 + threadIdx.x;
    if (i < 2097152) {                       // 8388608 x elems as float4
        float4 v = ((const float4*)x)[i];
        ushort4 o;
        o.x = f2bf(v.x); o.y = f2bf(v.y); o.z = f2bf(v.z); o.w = f2bf(v.w);
        ((ushort4*)xbf)[i] = o;
    }
    if (i < 81920) {                         // conv_w [k=f*64+c][u] -> wct[u][k]
        int u = i & 255, k = i >> 8;
        wct[u * 320 + k] = f2bf(conv_w[i]);
    }
    if (i < 129024) {                        // bias2[l2*256+o] = s2*(local_b - m2) + b2
        int o = i & 255;
        float s = g2[o] * rsqrtf(v2[o] + 1e-3f);
        bias2[i] = s * (local_b[i] - m2[o]) + b2[o];
    }
    if (i < 256) {
        float s1 = g1[i] * rsqrtf(v1[i] + 1e-3f);
        scale1[i] = s1;
        bias1[i] = s1 * (conv_b[i] - m1[i]) + b1[i];
        scale2[i] = g2[i] * rsqrtf(v2[i] + 1e-3f);
    }
}

// ---------------- conv GEMM: M=130048 (b*508+l1), K=320, N=256; y = relu(BN1(.)) bf16 ----
__global__ __launch_bounds__(256) void conv_gemm(
    const unsigned short* __restrict__ xbf, const unsigned short* __restrict__ wct,
    const float* __restrict__ scale1, const float* __restrict__ bias1,
    unsigned short* __restrict__ y)
{
    __shared__ unsigned short As[128 * 32];   // [m][k] stride 32 elems (64 B)
    __shared__ unsigned short Bs[128 * 32];   // [o][k] stride 32 elems
    const int tid = threadIdx.x;
    const int lane = tid & 63, wave = tid >> 6;
    const int quad = lane >> 4, c16 = lane & 15;
    const int wm = (wave >> 1) * 64, wn = (wave & 1) * 64;
    const int tn = blockIdx.x * 128;
    const int m0 = blockIdx.y * 128;
    const int sr = lane >> 2, sc = lane & 3;

    f32x4 acc[4][4];
#pragma unroll
    for (int i = 0; i < 4; ++i)
#pragma unroll
        for (int j = 0; j < 4; ++j) acc[i][j] = (f32x4){0.f, 0.f, 0.f, 0.f};

    for (int k0 = 0; k0 < 320; k0 += 32) {
        __syncthreads();
#pragma unroll
        for (int j = 0; j < 2; ++j) {
            int r = wave * 32 + j * 16 + sr;
            unsigned int m = (unsigned int)(m0 + r);
            const unsigned short* srca = xbf + (size_t)(m + 4u * (m / 508u)) * 64 + k0 + sc * 8;
            __builtin_amdgcn_global_load_lds(AS1(srca), AS3(As + (wave * 32 + j * 16) * 32), 16, 0, 0);
            const unsigned short* srcb = wct + (size_t)(tn + r) * 320 + k0 + sc * 8;
            __builtin_amdgcn_global_load_lds(AS1(srcb), AS3(Bs + (wave * 32 + j * 16) * 32), 16, 0, 0);
        }
        __syncthreads();
        short8 af[4], bfv[4];
#pragma unroll
        for (int i = 0; i < 4; ++i) af[i] = *(const short8*)&As[(wm + i * 16 + c16) * 32 + quad * 8];
#pragma unroll
        for (int j = 0; j < 4; ++j) bfv[j] = *(const short8*)&Bs[(wn + j * 16 + c16) * 32 + quad * 8];
#pragma unroll
        for (int i = 0; i < 4; ++i)
#pragma unroll
            for (int j = 0; j < 4; ++j)
                acc[i][j] = __builtin_amdgcn_mfma_f32_16x16x32_bf16(af[i], bfv[j], acc[i][j], 0, 0, 0);
    }

#pragma unroll
    for (int j = 0; j < 4; ++j) {
        int o = tn + wn + j * 16 + c16;
        float s = scale1[o], bb = bias1[o];
#pragma unroll
        for (int i = 0; i < 4; ++i) {
            int m = m0 + wm + i * 16 + quad * 4;
            size_t base = (size_t)m * 256 + o;
#pragma unroll
            for (int r = 0; r < 4; ++r) {
                float v = fmaxf(s * acc[i][j][r] + bb, 0.f);
                y[base + (size_t)r * 256] = f2bf(v);
            }
        }
    }
}

// ---------- local GEMM per l2: M=256(batch, FULL -> W read once), K=1280, N=128 ----------
// 512 threads / 8 waves, tile 256x128, grid (2, 504). W prefetched one K-step ahead
// into VGPRs during the MFMA phase (ping-pong, unroll-by-2).
__global__ __launch_bounds__(512) void local_gemm(
    const unsigned short* __restrict__ ybf, const float* __restrict__ lw,
    const float* __restrict__ scale2, const float* __restrict__ bias2,
    float* __restrict__ out)
{
    __shared__ unsigned short As[256 * 32];   // [b][k] stride 32 elems (16 KB)
    __shared__ unsigned short Bs[128 * 40];   // [o][k] stride 40 elems (10 KB, padded)
    const int tid = threadIdx.x;
    const int lane = tid & 63, wave = tid >> 6;         // 8 waves
    const int quad = lane >> 4, c16 = lane & 15;
    const int wm = (wave >> 1) * 64;                    // 0,64,128,192
    const int wn = (wave & 1) * 64;                     // 0,64
    const int tn = blockIdx.x * 128;
    const int l2 = blockIdx.y;
    const int sr = lane >> 2, sc = lane & 3;
    const int so = tid & 127, hk = tid >> 7;            // hk in 0..3

    const float* Wl = lw + (size_t)l2 * (1280 * 256) + tn;           // W[k][o] slice
    const unsigned short* Ab = ybf + ((size_t)0 * 508 + l2) * 256;   // + b*508*256 + k

    f32x4 acc[4][4];
#pragma unroll
    for (int i = 0; i < 4; ++i)
#pragma unroll
        for (int j = 0; j < 4; ++j) acc[i][j] = (f32x4){0.f, 0.f, 0.f, 0.f};

    float wA[8], wB[8];

#define LOADW(buf, kk)                                                         \
    _Pragma("unroll")                                                          \
    for (int p = 0; p < 2; ++p) {                                              \
        const float* ws = Wl + (size_t)((kk) + (hk * 2 + p) * 4) * 256 + so;   \
        buf[p * 4 + 0] = ws[0];                                                \
        buf[p * 4 + 1] = ws[256];                                              \
        buf[p * 4 + 2] = ws[512];                                              \
        buf[p * 4 + 3] = ws[768];                                              \
    }

#define STAGE_AND_MFMA(k0, buf, pk0, pbuf, doPrefetch)                          \
    do {                                                                        \
        __syncthreads();                                                        \
        _Pragma("unroll")                                                       \
        for (int j = 0; j < 2; ++j) {                                           \
            int r = wave * 32 + j * 16 + sr;                                    \
            const unsigned short* src =                                         \
                Ab + (size_t)r * (508 * 256) + (k0) + sc * 8;                   \
            __builtin_amdgcn_global_load_lds(                                   \
                AS1(src), AS3(As + (wave * 32 + j * 16) * 32), 16, 0, 0);       \
        }                                                                       \
        _Pragma("unroll")                                                       \
        for (int p = 0; p < 2; ++p) {                                           \
            uint2 pkv;                                                          \
            pkv.x = (unsigned int)f2bf(buf[p * 4 + 0]) |                        \
                    ((unsigned int)f2bf(buf[p * 4 + 1]) << 16);                 \
            pkv.y = (unsigned int)f2bf(buf[p * 4 + 2]) |                        \
                    ((unsigned int)f2bf(buf[p * 4 + 3]) << 16);                 \
            *(uint2*)&Bs[so * 40 + (hk * 2 + p) * 4] = pkv;                     \
        }                                                                       \
        __syncthreads();                                                        \
        if (doPrefetch) { LOADW(pbuf, pk0) }                                    \
        short8 af[4], bfv[4];                                                   \
        _Pragma("unroll")                                                       \
        for (int i = 0; i < 4; ++i)                                             \
            af[i] = *(const short8*)&As[(wm + i * 16 + c16) * 32 + quad * 8];   \
        _Pragma("unroll")                                                       \
        for (int j = 0; j < 4; ++j)                                             \
            bfv[j] = *(const short8*)&Bs[(wn + j * 16 + c16) * 40 + quad * 8];  \
        _Pragma("unroll")                                                       \
        for (int i = 0; i < 4; ++i)                                             \
            _Pragma("unroll")                                                   \
            for (int j = 0; j < 4; ++j)                                         \
                acc[i][j] = __builtin_amdgcn_mfma_f32_16x16x32_bf16(            \
                    af[i], bfv[j], acc[i][j], 0, 0, 0);                         \
    } while (0)

    LOADW(wA, 0)
    for (int k0 = 0; k0 < 1280; k0 += 64) {
        STAGE_AND_MFMA(k0, wA, k0 + 32, wB, 1);
        STAGE_AND_MFMA(k0 + 32, wB, k0 + 64, wA, (k0 + 64 < 1280));
    }
#undef LOADW
#undef STAGE_AND_MFMA

    const float* bp = bias2 + l2 * 256;
#pragma unroll
    for (int j = 0; j < 4; ++j) {
        int o = tn + wn + j * 16 + c16;
        float s = scale2[o], bb = bp[o];
#pragma unroll
        for (int i = 0; i < 4; ++i) {
            int b = wm + i * 16 + quad * 4;
            size_t base = ((size_t)b * 504 + l2) * 256 + o;
#pragma unroll
            for (int r = 0; r < 4; ++r) {
                float v = fmaxf(s * acc[i][j][r] + bb, 0.f);
                out[base + (size_t)r * (504 * 256)] = v;
            }
        }
    }
}

extern "C" void kernel_launch(void* const* d_in, const int* in_sizes, int n_in,
                              void* d_out, int out_size, void* d_ws, size_t ws_size,
                              hipStream_t stream) {
    const float* x      = (const float*)d_in[0];
    const float* conv_w = (const float*)d_in[1];
    const float* conv_b = (const float*)d_in[2];
    const float* g1     = (const float*)d_in[3];
    const float* b1     = (const float*)d_in[4];
    const float* m1     = (const float*)d_in[5];
    const float* v1     = (const float*)d_in[6];
    const float* lw     = (const float*)d_in[7];
    const float* lb     = (const float*)d_in[8];
    const float* g2     = (const float*)d_in[9];
    const float* b2     = (const float*)d_in[10];
    const float* m2     = (const float*)d_in[11];
    const float* v2     = (const float*)d_in[12];
    float* out = (float*)d_out;

    char* w = (char*)d_ws;
    unsigned short* xbf   = (unsigned short*)(w);             // 16,777,216 B
    unsigned short* wct   = (unsigned short*)(w + 16777216);  //    163,840 B
    float*          scale1 = (float*)(w + 16941056);          //      1,024 B
    float*          bias1  = (float*)(w + 16942080);          //      1,024 B
    float*          scale2 = (float*)(w + 16943104);          //      1,024 B
    float*          bias2  = (float*)(w + 16944128);          //    516,096 B
    unsigned short* ybf   = (unsigned short*)(w + 17460224);  // 66,584,576 B  (total ~84 MB)

    hipLaunchKernelGGL(prep_kernel, dim3(8192), dim3(256), 0, stream,
                       x, conv_w, conv_b, g1, b1, m1, v1, lb, g2, b2, m2, v2,
                       xbf, wct, scale1, bias1, scale2, bias2);
    hipLaunchKernelGGL(conv_gemm, dim3(2, 1016), dim3(256), 0, stream,
                       xbf, wct, scale1, bias1, ybf);
    hipLaunchKernelGGL(local_gemm, dim3(2, 504), dim3(512), 0, stream,
                       ybf, lw, scale2, bias2, out);
}